// Round 2
// baseline (824.207 us; speedup 1.0000x reference)
//
#include <hip/hip_runtime.h>

#define WIN 5
#define WW 25
#define DF 64
#define DC 256
#define HF 240
#define WF 320
#define LC 4800
#define NQ 16384
#define CH_STRIDE ((size_t)HF * WF)          // 76800
#define BS_STRIDE_F ((size_t)DF * CH_STRIDE)
#define FPAD 68                 // padded LDS window row stride (fallback kernel)

// d_ws float-index layout
#define WS_WFUSED 0                          // 256*64 floats
#define WS_BFUSED (DC * DF)                  // 64 floats (+pad)
#define WS_CPART  (DC * DF + 256)            // 32768*64 floats
#define WS_FT     (WS_CPART + 2 * NQ * DF)   // 2,113,792 -> channels-last maps
#define MAPSZ     ((size_t)4 * CH_STRIDE * DF)        // 19,660,800 floats per map
#define WS_NEEDED_BYTES (((size_t)WS_FT + 2 * MAPSZ) * 4)   // ~165.7 MB

// ---------------- K0: Wfused = Wd @ Wm_bot,  bfused = bm + bd @ Wm_bot ----
__global__ __launch_bounds__(64) void k0_fuse_weights(
    const float* __restrict__ Wd, const float* __restrict__ bd,
    const float* __restrict__ Wm, const float* __restrict__ bm,
    float* __restrict__ ws)
{
    const int r = blockIdx.x;      // 0..255 -> Wfused row; 256 -> bfused
    const int j = threadIdx.x;     // 0..63
    if (r < DC) {
        float acc = 0.f;
        #pragma unroll 8
        for (int i = 0; i < DF; ++i)
            acc += Wd[r * DF + i] * Wm[(DF + i) * DF + j];
        ws[WS_WFUSED + r * DF + j] = acc;
    } else {
        float acc = bm[j];
        #pragma unroll 8
        for (int i = 0; i < DF; ++i)
            acc += bd[i] * Wm[(DF + i) * DF + j];
        ws[WS_BFUSED + j] = acc;
    }
}

// ---------------- K1: cpart[row][j] = bfused[j] + c[row] . Wfused[:,j] -----
#define K1_ROWS 16
__global__ __launch_bounds__(256) void k1_cpart(
    const float* __restrict__ c0, const float* __restrict__ c1,
    const int* __restrict__ b_ids, const int* __restrict__ ci,
    float* __restrict__ ws)
{
    const float* __restrict__ wfused = ws + WS_WFUSED;
    const float* __restrict__ bfused = ws + WS_BFUSED;
    float* __restrict__ cpart = ws + WS_CPART;

    const int t  = threadIdx.x;
    const int j  = t & 63;         // output channel
    const int kc = t >> 6;         // K-quarter 0..3

    float wf[64];
    #pragma unroll
    for (int k = 0; k < 64; ++k)
        wf[k] = wfused[(kc * 64 + k) * DF + j];

    __shared__ float c_sh[DC];
    __shared__ float red[256];

    for (int ri = 0; ri < K1_ROWS; ++ri) {
        const int row = blockIdx.x * K1_ROWS + ri;
        const int s = row >> 14;
        const int n = row & (NQ - 1);
        const float* __restrict__ fc = s ? c1 : c0;
        const int b  = b_ids[n];
        const int cc = ci[n];

        c_sh[t] = fc[((size_t)b * LC + cc) * DC + t];   // coalesced stage
        __syncthreads();

        float acc = 0.f;
        #pragma unroll
        for (int k4 = 0; k4 < 16; ++k4) {
            float4 cv = *(const float4*)&c_sh[kc * 64 + k4 * 4];
            acc += cv.x * wf[k4 * 4 + 0] + cv.y * wf[k4 * 4 + 1] +
                   cv.z * wf[k4 * 4 + 2] + cv.w * wf[k4 * 4 + 3];
        }
        red[t] = acc;
        __syncthreads();

        if (t < 64) {
            cpart[(size_t)row * DF + t] =
                red[t] + red[t + 64] + red[t + 128] + red[t + 192] + bfused[t];
        }
    }
}

// ---------------- KT: channels-first -> channels-last transpose -----------
__global__ __launch_bounds__(256) void kt_transpose(
    const float* __restrict__ f0, const float* __restrict__ f1,
    float* __restrict__ ws)
{
    const int t = threadIdx.x;
    const float* __restrict__ src = blockIdx.z ? f1 : f0;
    float* __restrict__ fT = ws + WS_FT + (size_t)blockIdx.z * MAPSZ;
    const int b  = blockIdx.y;
    const int p0 = blockIdx.x * 64;

    __shared__ float tile[64][65];

    const float* __restrict__ sb = src + (size_t)b * BS_STRIDE_F;
    const int g  = t >> 4;           // 0..15
    const int x4 = t & 15;
    #pragma unroll
    for (int q = 0; q < 4; ++q) {
        const int c = g + q * 16;
        const float4 v = *(const float4*)&sb[(size_t)c * CH_STRIDE + p0 + x4 * 4];
        tile[c][x4 * 4 + 0] = v.x; tile[c][x4 * 4 + 1] = v.y;
        tile[c][x4 * 4 + 2] = v.z; tile[c][x4 * 4 + 3] = v.w;
    }
    __syncthreads();
    float* __restrict__ ob = fT + ((size_t)b * CH_STRIDE + p0) * DF;
    #pragma unroll
    for (int q = 0; q < 4; ++q) {
        const int p  = g + q * 16;
        const int cc = x4 * 4;
        const float4 v = make_float4(tile[cc + 0][p], tile[cc + 1][p],
                                     tile[cc + 2][p], tile[cc + 3][p]);
        *(float4*)&ob[(size_t)p * DF + cc] = v;
    }
}

// ---------------- K2S: main — lane=channel, Wm col in VGPRs, uniform f ----
// out[w][j] = cpart[gw][j] + sum_i f[w][i] * Wm_top[i][j]
// lane j holds Wm[:,j] in 64 VGPRs; f[w][i] is wave-uniform -> SMEM loads.
// No LDS, no __syncthreads, zero wasted FMAs.
__global__ __launch_bounds__(256) void k2_scalar(
    const float* __restrict__ Wm,
    const int* __restrict__ b_ids, const int* __restrict__ cy,
    const int* __restrict__ cx,
    const float* __restrict__ ws, float* __restrict__ out)
{
    const float* __restrict__ cpart = ws + WS_CPART;

    const int t    = threadIdx.x;
    const int lane = t & 63;
    const int wave = t >> 6;

    const int gw = blockIdx.x * 4 + wave;       // 0..32767 = s*NQ + n
    const int s  = gw >> 14;
    const int n  = gw & (NQ - 1);
    const float* __restrict__ fT = ws + WS_FT + (size_t)s * MAPSZ;

    // wave-uniform scalars (force SGPR so f-loads get uniform addresses)
    const int b = __builtin_amdgcn_readfirstlane(b_ids[n]);
    const int Y = __builtin_amdgcn_readfirstlane(cy[n]);
    const int X = __builtin_amdgcn_readfirstlane(cx[n]);
    const int base = ((b * HF + (Y - 2)) * WF + (X - 2)) * DF;  // float idx, fits 32b
    const float4* __restrict__ fq = (const float4*)(fT + base); // uniform, 256B-aligned

    // ---- Wm column j in registers (float2 pairs over i) ----
    float2 wm2[32];
    #pragma unroll
    for (int i2 = 0; i2 < 32; ++i2) {
        wm2[i2].x = Wm[(2 * i2 + 0) * DF + lane];   // coalesced 256B per i
        wm2[i2].y = Wm[(2 * i2 + 1) * DF + lane];
    }

    const float cp = cpart[(size_t)gw * DF + lane];

    float2 acc[WW];
    #pragma unroll
    for (int w = 0; w < WW; ++w) { acc[w].x = 0.f; acc[w].y = 0.f; }

    // ---- 25 windows x 64 channels: 1600 FMAs/lane, f via uniform loads ----
    #pragma unroll
    for (int w = 0; w < WW; ++w) {
        const int wy = w / 5;                    // compile-time
        const int wx = w - wy * 5;
        const int ro = (wy * WF + wx) * (DF / 4); // float4 offset, compile-time
        #pragma unroll
        for (int i4 = 0; i4 < 16; ++i4) {
            const float4 fv = fq[ro + i4];       // uniform -> s_load_dwordx4/x16
            // paired to invite v_pk_fma_f32
            acc[w].x += fv.x * wm2[2 * i4 + 0].x;
            acc[w].y += fv.y * wm2[2 * i4 + 0].y;
            acc[w].x += fv.z * wm2[2 * i4 + 1].x;
            acc[w].y += fv.w * wm2[2 * i4 + 1].y;
        }
    }

    // ---- store: per w, lanes 0..63 cover 256B contiguous ----
    float* __restrict__ ob = out + (size_t)gw * (WW * DF);
    #pragma unroll
    for (int w = 0; w < WW; ++w)
        ob[w * DF + lane] = acc[w].x + acc[w].y + cp;
}

// ---------------- K2 (fallback): original gather from channels-first ------
__global__ __launch_bounds__(256) void k2_main(
    const float* __restrict__ f0, const float* __restrict__ f1,
    const float* __restrict__ Wm,
    const int* __restrict__ b_ids, const int* __restrict__ cy,
    const int* __restrict__ cx,
    const float* __restrict__ ws, float* __restrict__ out)
{
    const float* __restrict__ cpart = ws + WS_CPART;

    const int t    = threadIdx.x;
    const int lane = t & 63;
    const int wave = t >> 6;

    __shared__ float wm_sh[DF * DF];
    __shared__ float f_sh[4 * WW * FPAD];

    {
        const float4* src = (const float4*)Wm;
        float4* dst = (float4*)wm_sh;
        #pragma unroll
        for (int q = 0; q < 4; ++q)
            dst[t + q * 256] = src[t + q * 256];
    }

    const int gw = blockIdx.x * 4 + wave;
    const int s  = gw >> 14;
    const int n  = gw & (NQ - 1);
    const float* __restrict__ ff = s ? f1 : f0;
    const int b = b_ids[n];
    const int Y = cy[n];
    const int X = cx[n];

    float* fw = f_sh + wave * WW * FPAD;
    const float* fwin = ff + (size_t)b * BS_STRIDE_F + (size_t)(Y - 2) * WF + (X - 2);
    #pragma unroll
    for (int r = 0; r < 25; ++r) {
        const int e = lane + r * 64;
        const int i = e / 25;
        const int w = e - i * 25;
        const int wy = w / 5;
        const int wx = w - wy * 5;
        fw[w * FPAD + i] = fwin[(size_t)i * CH_STRIDE + wy * WF + wx];
    }
    __syncthreads();

    const int j0 = (lane & 15) * 4;
    const int w0 = lane >> 4;

    const float4 cp = *(const float4*)&cpart[(size_t)gw * DF + j0];
    float4 acc[7];
    #pragma unroll
    for (int u = 0; u < 7; ++u) acc[u] = cp;

    #pragma unroll 4
    for (int i = 0; i < DF; i += 4) {
        const float4 m0 = *(const float4*)&wm_sh[(i + 0) * DF + j0];
        const float4 m1 = *(const float4*)&wm_sh[(i + 1) * DF + j0];
        const float4 m2 = *(const float4*)&wm_sh[(i + 2) * DF + j0];
        const float4 m3 = *(const float4*)&wm_sh[(i + 3) * DF + j0];
        #pragma unroll
        for (int u = 0; u < 7; ++u) {
            const int w = w0 + 4 * u;
            if (w < WW) {
                const float4 fv = *(const float4*)&fw[w * FPAD + i];
                acc[u].x += fv.x * m0.x + fv.y * m1.x + fv.z * m2.x + fv.w * m3.x;
                acc[u].y += fv.x * m0.y + fv.y * m1.y + fv.z * m2.y + fv.w * m3.y;
                acc[u].z += fv.x * m0.z + fv.y * m1.z + fv.z * m2.z + fv.w * m3.z;
                acc[u].w += fv.x * m0.w + fv.y * m1.w + fv.z * m2.w + fv.w * m3.w;
            }
        }
    }

    float* ob = out + (size_t)gw * (WW * DF);
    #pragma unroll
    for (int u = 0; u < 7; ++u) {
        const int w = w0 + 4 * u;
        if (w < WW)
            *(float4*)&ob[w * DF + j0] = acc[u];
    }
}

extern "C" void kernel_launch(void* const* d_in, const int* in_sizes, int n_in,
                              void* d_out, int out_size, void* d_ws, size_t ws_size,
                              hipStream_t stream) {
    const float* f0 = (const float*)d_in[0];
    const float* f1 = (const float*)d_in[1];
    const float* c0 = (const float*)d_in[2];
    const float* c1 = (const float*)d_in[3];
    const float* Wd = (const float*)d_in[4];
    const float* bd = (const float*)d_in[5];
    const float* Wm = (const float*)d_in[6];
    const float* bm = (const float*)d_in[7];
    const int* b_ids = (const int*)d_in[8];
    const int* cyv   = (const int*)d_in[9];
    const int* cxv   = (const int*)d_in[10];
    const int* civ   = (const int*)d_in[11];
    float* out = (float*)d_out;
    float* ws  = (float*)d_ws;

    const bool big_ws = (ws_size >= WS_NEEDED_BYTES);

    if (big_ws) {
        kt_transpose<<<dim3(CH_STRIDE / 64, 4, 2), dim3(256), 0, stream>>>(f0, f1, ws);
    }
    k0_fuse_weights<<<dim3(DC + 1), dim3(64), 0, stream>>>(Wd, bd, Wm, bm, ws);
    k1_cpart<<<dim3(2 * NQ / K1_ROWS), dim3(256), 0, stream>>>(c0, c1, b_ids, civ, ws);
    if (big_ws) {
        k2_scalar<<<dim3(2 * NQ / 4), dim3(256), 0, stream>>>(
            Wm, b_ids, cyv, cxv, ws, out);
    } else {
        k2_main<<<dim3(2 * NQ / 4), dim3(256), 0, stream>>>(
            f0, f1, Wm, b_ids, cyv, cxv, ws, out);
    }
}

// Round 3
// 461.069 us; speedup vs baseline: 1.7876x; 1.7876x over previous
//
#include <hip/hip_runtime.h>

#define WIN 5
#define WW 25
#define DF 64
#define DC 256
#define HF 240
#define WF 320
#define LC 4800
#define NQ 16384
#define CH_STRIDE ((size_t)HF * WF)          // 76800
#define BS_STRIDE_F ((size_t)DF * CH_STRIDE)
#define FPAD 68          // fp32 fallback LDS pad
#define FB 72            // bf16 LDS row stride (144 B) for k2_mfma

// d_ws float-index layout
#define WS_WFUSED 0                          // 256*64 floats
#define WS_BFUSED (DC * DF)                  // 64 floats (+pad)
#define WS_CPART  (DC * DF + 256)            // 32768*64 floats
#define WS_WMT    (WS_CPART + 2 * NQ * DF)   // 64x64 bf16 WmT (2048 floats)
#define WS_FT     (WS_WMT + 2048)            // bf16 channels-last maps
#define MAPSZ_US  ((size_t)4 * CH_STRIDE * DF)       // 19,660,800 ushorts/map
#define WS_NEEDED_BYTES ((size_t)WS_FT * 4 + 2 * MAPSZ_US * 2)   // ~87 MB

typedef __attribute__((ext_vector_type(8))) short bf16x8;   // 8 bf16 (4 VGPR)
typedef __attribute__((ext_vector_type(4))) float f32x4;

__device__ __forceinline__ unsigned short f2bf(float x) {   // RNE f32->bf16
    unsigned int u = __float_as_uint(x);
    u += 0x7FFFu + ((u >> 16) & 1u);
    return (unsigned short)(u >> 16);
}

// ---------------- K0: Wfused = Wd @ Wm_bot, bfused, WmT(bf16) -------------
__global__ __launch_bounds__(64) void k0_fuse_weights(
    const float* __restrict__ Wd, const float* __restrict__ bd,
    const float* __restrict__ Wm, const float* __restrict__ bm,
    float* __restrict__ ws)
{
    const int r = blockIdx.x;      // 0..255 Wfused row; 256 bfused; 257 WmT
    const int j = threadIdx.x;     // 0..63
    if (r < DC) {
        float acc = 0.f;
        #pragma unroll 8
        for (int i = 0; i < DF; ++i)
            acc += Wd[r * DF + i] * Wm[(DF + i) * DF + j];
        ws[WS_WFUSED + r * DF + j] = acc;
    } else if (r == DC) {
        float acc = bm[j];
        #pragma unroll 8
        for (int i = 0; i < DF; ++i)
            acc += bd[i] * Wm[(DF + i) * DF + j];
        ws[WS_BFUSED + j] = acc;
    } else {
        // WmT[j][i] = bf16(Wm_top[i][j])  (8 KB, once)
        unsigned short* __restrict__ wmT = (unsigned short*)(ws + WS_WMT);
        #pragma unroll 8
        for (int i = 0; i < DF; ++i)
            wmT[j * DF + i] = f2bf(Wm[i * DF + j]);
    }
}

// ---------------- K1: cpart[row][j] = bfused[j] + c[row] . Wfused[:,j] -----
#define K1_ROWS 16
__global__ __launch_bounds__(256) void k1_cpart(
    const float* __restrict__ c0, const float* __restrict__ c1,
    const int* __restrict__ b_ids, const int* __restrict__ ci,
    float* __restrict__ ws)
{
    const float* __restrict__ wfused = ws + WS_WFUSED;
    const float* __restrict__ bfused = ws + WS_BFUSED;
    float* __restrict__ cpart = ws + WS_CPART;

    const int t  = threadIdx.x;
    const int j  = t & 63;
    const int kc = t >> 6;

    float wf[64];
    #pragma unroll
    for (int k = 0; k < 64; ++k)
        wf[k] = wfused[(kc * 64 + k) * DF + j];

    __shared__ float c_sh[DC];
    __shared__ float red[256];

    for (int ri = 0; ri < K1_ROWS; ++ri) {
        const int row = blockIdx.x * K1_ROWS + ri;
        const int s = row >> 14;
        const int n = row & (NQ - 1);
        const float* __restrict__ fc = s ? c1 : c0;
        const int b  = b_ids[n];
        const int cc = ci[n];

        c_sh[t] = fc[((size_t)b * LC + cc) * DC + t];
        __syncthreads();

        float acc = 0.f;
        #pragma unroll
        for (int k4 = 0; k4 < 16; ++k4) {
            float4 cv = *(const float4*)&c_sh[kc * 64 + k4 * 4];
            acc += cv.x * wf[k4 * 4 + 0] + cv.y * wf[k4 * 4 + 1] +
                   cv.z * wf[k4 * 4 + 2] + cv.w * wf[k4 * 4 + 3];
        }
        red[t] = acc;
        __syncthreads();

        if (t < 64) {
            cpart[(size_t)row * DF + t] =
                red[t] + red[t + 64] + red[t + 128] + red[t + 192] + bfused[t];
        }
    }
}

// ---------------- KT: channels-first fp32 -> channels-last bf16 -----------
__global__ __launch_bounds__(256) void kt_transpose(
    const float* __restrict__ f0, const float* __restrict__ f1,
    float* __restrict__ ws)
{
    const int t = threadIdx.x;
    const float* __restrict__ src = blockIdx.z ? f1 : f0;
    unsigned short* __restrict__ fT =
        (unsigned short*)(ws + WS_FT) + (size_t)blockIdx.z * MAPSZ_US;
    const int b  = blockIdx.y;
    const int p0 = blockIdx.x * 64;

    __shared__ float tile[64][65];

    const float* __restrict__ sb = src + (size_t)b * BS_STRIDE_F;
    const int g  = t >> 4;           // 0..15
    const int x4 = t & 15;
    #pragma unroll
    for (int q = 0; q < 4; ++q) {
        const int c = g + q * 16;
        const float4 v = *(const float4*)&sb[(size_t)c * CH_STRIDE + p0 + x4 * 4];
        tile[c][x4 * 4 + 0] = v.x; tile[c][x4 * 4 + 1] = v.y;
        tile[c][x4 * 4 + 2] = v.z; tile[c][x4 * 4 + 3] = v.w;
    }
    __syncthreads();
    unsigned short* __restrict__ ob = fT + ((size_t)b * CH_STRIDE + p0) * DF;
    #pragma unroll
    for (int q = 0; q < 4; ++q) {
        const int p  = g + q * 16;
        const int cc = x4 * 4;
        ushort4 h;
        h.x = f2bf(tile[cc + 0][p]); h.y = f2bf(tile[cc + 1][p]);
        h.z = f2bf(tile[cc + 2][p]); h.w = f2bf(tile[cc + 3][p]);
        *(ushort4*)&ob[(size_t)p * DF + cc] = h;
    }
}

// ---------------- K2M: main — MFMA 25x64x64 per wave-query ----------------
// out[w][j] = cpart[gw][j] + sum_i f[w][i]*Wm_top[i][j]
// A = f (M=25 pad 32, K=64) bf16 from f_sh; B = Wm_top via WmT bf16.
// mfma_f32_16x16x32_bf16: A lane: row=lane&15, k=(lane>>4)*8+e
//                         B lane: col=lane&15, k=(lane>>4)*8+e
//                         D lane: col=lane&15, row=(lane>>4)*4+r (verified)
__global__ __launch_bounds__(256) void k2_mfma(
    const int* __restrict__ b_ids, const int* __restrict__ cy,
    const int* __restrict__ cx,
    const float* __restrict__ ws, float* __restrict__ out)
{
    const float* __restrict__ cpart = ws + WS_CPART;
    const unsigned short* __restrict__ wmT = (const unsigned short*)(ws + WS_WMT);

    const int t    = threadIdx.x;
    const int lane = t & 63;
    const int wave = t >> 6;

    __shared__ unsigned short wmT_sh[DF * FB];      // 9216 B
    __shared__ unsigned short f_sh[4 * WW * FB];    // 14400 B

    // ---- stage WmT (block-coop): 64 rows x 8 segs of 8 bf16 ----
    #pragma unroll
    for (int q = 0; q < 2; ++q) {
        const int idx = t + q * 256;                // 0..511
        const int j   = idx >> 3;
        const int sg  = idx & 7;
        *(uint4*)&wmT_sh[j * FB + sg * 8] = *(const uint4*)&wmT[j * DF + sg * 8];
    }

    // ---- wave-private window gather: 200 x 16B lane-loads ----
    const int gw = blockIdx.x * 4 + wave;           // s*NQ + n
    const int s  = gw >> 14;
    const int n  = gw & (NQ - 1);
    const unsigned short* __restrict__ fTm =
        (const unsigned short*)(ws + WS_FT) + (size_t)s * MAPSZ_US;
    const int b = b_ids[n];
    const int Y = cy[n];
    const int X = cx[n];
    const int base = ((b * HF + (Y - 2)) * WF + (X - 2)) * DF;  // ushort idx

    unsigned short* fw = f_sh + wave * WW * FB;
    #pragma unroll
    for (int r = 0; r < 4; ++r) {
        const int e = lane + r * 64;                // 16B-seg idx 0..255
        if (e < 200) {
            const int w  = e >> 3;                  // window pos 0..24
            const int sg = e & 7;                   // 8-bf16 segment
            const int wy = (w * 13) >> 6;           // w/5
            const int wx = w - wy * 5;
            *(uint4*)&fw[w * FB + sg * 8] =
                *(const uint4*)&fTm[base + (wy * WF + wx) * DF + sg * 8];
        }
    }
    __syncthreads();

    // ---- MFMA: 2 Mtiles x 4 Ntiles x 2 Ksteps ----
    const int row16 = lane & 15;
    const int kb    = lane >> 4;                    // k-block / D row-group
    const int r1row = (row16 < 9) ? (16 + row16) : 24;   // Mtile1 row clamp

    f32x4 acc[2][4];
    #pragma unroll
    for (int m = 0; m < 2; ++m)
        #pragma unroll
        for (int nn = 0; nn < 4; ++nn)
            acc[m][nn] = (f32x4){0.f, 0.f, 0.f, 0.f};

    #pragma unroll
    for (int ks = 0; ks < 2; ++ks) {
        const int k0 = ks * 32 + kb * 8;
        const bf16x8 a0 = *(const bf16x8*)&fw[row16 * FB + k0];
        const bf16x8 a1 = *(const bf16x8*)&fw[r1row * FB + k0];
        #pragma unroll
        for (int nn = 0; nn < 4; ++nn) {
            const bf16x8 bfrag = *(const bf16x8*)&wmT_sh[(nn * 16 + row16) * FB + k0];
            acc[0][nn] = __builtin_amdgcn_mfma_f32_16x16x32_bf16(a0, bfrag, acc[0][nn], 0, 0, 0);
            acc[1][nn] = __builtin_amdgcn_mfma_f32_16x16x32_bf16(a1, bfrag, acc[1][nn], 0, 0, 0);
        }
    }

    // ---- epilogue: + cpart, store (w guarded) ----
    const float* __restrict__ cprow = cpart + (size_t)gw * DF;
    float* __restrict__ ob = out + (size_t)gw * (WW * DF);
    #pragma unroll
    for (int nn = 0; nn < 4; ++nn) {
        const float cp = cprow[nn * 16 + row16];
        #pragma unroll
        for (int m = 0; m < 2; ++m) {
            #pragma unroll
            for (int r = 0; r < 4; ++r) {
                const int w = m * 16 + kb * 4 + r;  // D row = (lane>>4)*4+r
                if (w < WW)
                    ob[w * DF + nn * 16 + row16] = acc[m][nn][r] + cp;
            }
        }
    }
}

// ---------------- K2 (fallback): fp32 gather from channels-first ----------
__global__ __launch_bounds__(256) void k2_main(
    const float* __restrict__ f0, const float* __restrict__ f1,
    const float* __restrict__ Wm,
    const int* __restrict__ b_ids, const int* __restrict__ cy,
    const int* __restrict__ cx,
    const float* __restrict__ ws, float* __restrict__ out)
{
    const float* __restrict__ cpart = ws + WS_CPART;

    const int t    = threadIdx.x;
    const int lane = t & 63;
    const int wave = t >> 6;

    __shared__ float wm_sh[DF * DF];
    __shared__ float f_sh[4 * WW * FPAD];

    {
        const float4* src = (const float4*)Wm;
        float4* dst = (float4*)wm_sh;
        #pragma unroll
        for (int q = 0; q < 4; ++q)
            dst[t + q * 256] = src[t + q * 256];
    }

    const int gw = blockIdx.x * 4 + wave;
    const int s  = gw >> 14;
    const int n  = gw & (NQ - 1);
    const float* __restrict__ ff = s ? f1 : f0;
    const int b = b_ids[n];
    const int Y = cy[n];
    const int X = cx[n];

    float* fw = f_sh + wave * WW * FPAD;
    const float* fwin = ff + (size_t)b * BS_STRIDE_F + (size_t)(Y - 2) * WF + (X - 2);
    #pragma unroll
    for (int r = 0; r < 25; ++r) {
        const int e = lane + r * 64;
        const int i = e / 25;
        const int w = e - i * 25;
        const int wy = w / 5;
        const int wx = w - wy * 5;
        fw[w * FPAD + i] = fwin[(size_t)i * CH_STRIDE + wy * WF + wx];
    }
    __syncthreads();

    const int j0 = (lane & 15) * 4;
    const int w0 = lane >> 4;

    const float4 cp = *(const float4*)&cpart[(size_t)gw * DF + j0];
    float4 acc[7];
    #pragma unroll
    for (int u = 0; u < 7; ++u) acc[u] = cp;

    #pragma unroll 4
    for (int i = 0; i < DF; i += 4) {
        const float4 m0 = *(const float4*)&wm_sh[(i + 0) * DF + j0];
        const float4 m1 = *(const float4*)&wm_sh[(i + 1) * DF + j0];
        const float4 m2 = *(const float4*)&wm_sh[(i + 2) * DF + j0];
        const float4 m3 = *(const float4*)&wm_sh[(i + 3) * DF + j0];
        #pragma unroll
        for (int u = 0; u < 7; ++u) {
            const int w = w0 + 4 * u;
            if (w < WW) {
                const float4 fv = *(const float4*)&fw[w * FPAD + i];
                acc[u].x += fv.x * m0.x + fv.y * m1.x + fv.z * m2.x + fv.w * m3.x;
                acc[u].y += fv.x * m0.y + fv.y * m1.y + fv.z * m2.y + fv.w * m3.y;
                acc[u].z += fv.x * m0.z + fv.y * m1.z + fv.z * m2.z + fv.w * m3.z;
                acc[u].w += fv.x * m0.w + fv.y * m1.w + fv.z * m2.w + fv.w * m3.w;
            }
        }
    }

    float* ob = out + (size_t)gw * (WW * DF);
    #pragma unroll
    for (int u = 0; u < 7; ++u) {
        const int w = w0 + 4 * u;
        if (w < WW)
            *(float4*)&ob[w * DF + j0] = acc[u];
    }
}

extern "C" void kernel_launch(void* const* d_in, const int* in_sizes, int n_in,
                              void* d_out, int out_size, void* d_ws, size_t ws_size,
                              hipStream_t stream) {
    const float* f0 = (const float*)d_in[0];
    const float* f1 = (const float*)d_in[1];
    const float* c0 = (const float*)d_in[2];
    const float* c1 = (const float*)d_in[3];
    const float* Wd = (const float*)d_in[4];
    const float* bd = (const float*)d_in[5];
    const float* Wm = (const float*)d_in[6];
    const float* bm = (const float*)d_in[7];
    const int* b_ids = (const int*)d_in[8];
    const int* cyv   = (const int*)d_in[9];
    const int* cxv   = (const int*)d_in[10];
    const int* civ   = (const int*)d_in[11];
    float* out = (float*)d_out;
    float* ws  = (float*)d_ws;

    const bool big_ws = (ws_size >= WS_NEEDED_BYTES);

    if (big_ws) {
        kt_transpose<<<dim3(CH_STRIDE / 64, 4, 2), dim3(256), 0, stream>>>(f0, f1, ws);
    }
    k0_fuse_weights<<<dim3(DC + 2), dim3(64), 0, stream>>>(Wd, bd, Wm, bm, ws);
    k1_cpart<<<dim3(2 * NQ / K1_ROWS), dim3(256), 0, stream>>>(c0, c1, b_ids, civ, ws);
    if (big_ws) {
        k2_mfma<<<dim3(2 * NQ / 4), dim3(256), 0, stream>>>(
            b_ids, cyv, cxv, ws, out);
    } else {
        k2_main<<<dim3(2 * NQ / 4), dim3(256), 0, stream>>>(
            f0, f1, Wm, b_ids, cyv, cxv, ws, out);
    }
}

// Round 5
// 438.137 us; speedup vs baseline: 1.8812x; 1.0523x over previous
//
#include <hip/hip_runtime.h>

#define WIN 5
#define WW 25
#define DF 64
#define DC 256
#define HF 240
#define WF 320
#define LC 4800
#define NQ 16384
#define CH_STRIDE ((size_t)HF * WF)          // 76800
#define BS_STRIDE_F ((size_t)DF * CH_STRIDE)
#define FPAD 68          // fp32 fallback LDS pad

// d_ws float-index layout
#define WS_WFUSED 0                          // 256*64 floats
#define WS_BFUSED (DC * DF)                  // 64 floats (+pad)
#define WS_CPART  (DC * DF + 256)            // 32768*64 floats
#define WS_WMT    (WS_CPART + 2 * NQ * DF)   // 64x64 bf16 WmT (2048 floats)
#define WS_FT     (WS_WMT + 2048)            // bf16 channels-last maps
#define MAPSZ_US  ((size_t)4 * CH_STRIDE * DF)       // 19,660,800 ushorts/map
#define WS_NEEDED_BYTES ((size_t)WS_FT * 4 + 2 * MAPSZ_US * 2)   // ~87 MB

typedef __attribute__((ext_vector_type(8))) short bf16x8;   // 8 bf16 (4 VGPR)
typedef __attribute__((ext_vector_type(4))) float f32x4;

__device__ __forceinline__ unsigned short f2bf(float x) {   // RNE f32->bf16
    unsigned int u = __float_as_uint(x);
    u += 0x7FFFu + ((u >> 16) & 1u);
    return (unsigned short)(u >> 16);
}

// ---------------- K0: Wfused = Wd @ Wm_bot, bfused, WmT(bf16) -------------
__global__ __launch_bounds__(64) void k0_fuse_weights(
    const float* __restrict__ Wd, const float* __restrict__ bd,
    const float* __restrict__ Wm, const float* __restrict__ bm,
    float* __restrict__ ws)
{
    const int r = blockIdx.x;      // 0..255 Wfused row; 256 bfused; 257 WmT
    const int j = threadIdx.x;     // 0..63
    if (r < DC) {
        float acc = 0.f;
        #pragma unroll 8
        for (int i = 0; i < DF; ++i)
            acc += Wd[r * DF + i] * Wm[(DF + i) * DF + j];
        ws[WS_WFUSED + r * DF + j] = acc;
    } else if (r == DC) {
        float acc = bm[j];
        #pragma unroll 8
        for (int i = 0; i < DF; ++i)
            acc += bd[i] * Wm[(DF + i) * DF + j];
        ws[WS_BFUSED + j] = acc;
    } else {
        // WmT[j][i] = bf16(Wm_top[i][j])  (8 KB, once)
        unsigned short* __restrict__ wmT = (unsigned short*)(ws + WS_WMT);
        #pragma unroll 8
        for (int i = 0; i < DF; ++i)
            wmT[j * DF + i] = f2bf(Wm[i * DF + j]);
    }
}

// ---------------- K1: cpart[row][j] = bfused[j] + c[row] . Wfused[:,j] -----
#define K1_ROWS 16
__global__ __launch_bounds__(256) void k1_cpart(
    const float* __restrict__ c0, const float* __restrict__ c1,
    const int* __restrict__ b_ids, const int* __restrict__ ci,
    float* __restrict__ ws)
{
    const float* __restrict__ wfused = ws + WS_WFUSED;
    const float* __restrict__ bfused = ws + WS_BFUSED;
    float* __restrict__ cpart = ws + WS_CPART;

    const int t  = threadIdx.x;
    const int j  = t & 63;
    const int kc = t >> 6;

    float wf[64];
    #pragma unroll
    for (int k = 0; k < 64; ++k)
        wf[k] = wfused[(kc * 64 + k) * DF + j];

    __shared__ float c_sh[DC];
    __shared__ float red[256];

    for (int ri = 0; ri < K1_ROWS; ++ri) {
        const int row = blockIdx.x * K1_ROWS + ri;
        const int s = row >> 14;
        const int n = row & (NQ - 1);
        const float* __restrict__ fc = s ? c1 : c0;
        const int b  = b_ids[n];
        const int cc = ci[n];

        c_sh[t] = fc[((size_t)b * LC + cc) * DC + t];
        __syncthreads();

        float acc = 0.f;
        #pragma unroll
        for (int k4 = 0; k4 < 16; ++k4) {
            float4 cv = *(const float4*)&c_sh[kc * 64 + k4 * 4];
            acc += cv.x * wf[k4 * 4 + 0] + cv.y * wf[k4 * 4 + 1] +
                   cv.z * wf[k4 * 4 + 2] + cv.w * wf[k4 * 4 + 3];
        }
        red[t] = acc;
        __syncthreads();

        if (t < 64) {
            cpart[(size_t)row * DF + t] =
                red[t] + red[t + 64] + red[t + 128] + red[t + 192] + bfused[t];
        }
    }
}

// ---------------- KT: channels-first fp32 -> channels-last bf16 -----------
// nontemporal source reads: each fp32 line touched once; keep L3 space for
// the bf16 output maps that k2 re-reads.
__global__ __launch_bounds__(256) void kt_transpose(
    const float* __restrict__ f0, const float* __restrict__ f1,
    float* __restrict__ ws)
{
    const int t = threadIdx.x;
    const float* __restrict__ src = blockIdx.z ? f1 : f0;
    unsigned short* __restrict__ fT =
        (unsigned short*)(ws + WS_FT) + (size_t)blockIdx.z * MAPSZ_US;
    const int b  = blockIdx.y;
    const int p0 = blockIdx.x * 64;

    __shared__ float tile[64][65];

    const float* __restrict__ sb = src + (size_t)b * BS_STRIDE_F;
    const int g  = t >> 4;           // 0..15
    const int x4 = t & 15;
    #pragma unroll
    for (int q = 0; q < 4; ++q) {
        const int c = g + q * 16;
        const f32x4 v = __builtin_nontemporal_load(
            (const f32x4*)&sb[(size_t)c * CH_STRIDE + p0 + x4 * 4]);
        tile[c][x4 * 4 + 0] = v[0]; tile[c][x4 * 4 + 1] = v[1];
        tile[c][x4 * 4 + 2] = v[2]; tile[c][x4 * 4 + 3] = v[3];
    }
    __syncthreads();
    unsigned short* __restrict__ ob = fT + ((size_t)b * CH_STRIDE + p0) * DF;
    #pragma unroll
    for (int q = 0; q < 4; ++q) {
        const int p  = g + q * 16;
        const int cc = x4 * 4;
        ushort4 h;
        h.x = f2bf(tile[cc + 0][p]); h.y = f2bf(tile[cc + 1][p]);
        h.z = f2bf(tile[cc + 2][p]); h.w = f2bf(tile[cc + 3][p]);
        *(ushort4*)&ob[(size_t)p * DF + cc] = h;      // cacheable: k2 reads it
    }
}

// ---------------- K2M: main — MFMA, zero LDS, direct-register fragments ---
// out[w][j] = cpart[gw][j] + sum_i f[w][i]*Wm_top[i][j]
// mfma_f32_16x16x32_bf16 layouts (verified round 3):
//   A lane: row=lane&15, k=(lane>>4)*8+e  -> 16B contiguous in fT map
//   B lane: col=lane&15, k=(lane>>4)*8+e  -> 16B contiguous in WmT[j][i]
//   D lane: col=lane&15, row=(lane>>4)*4+r
// B-frags are query-invariant per lane -> registers, loaded once.
// A-frags load straight from the channels-last map (no LDS, no barriers).
__global__ __launch_bounds__(256) void k2_mfma(
    const int* __restrict__ b_ids, const int* __restrict__ cy,
    const int* __restrict__ cx,
    const float* __restrict__ ws, float* __restrict__ out)
{
    const float* __restrict__ cpart = ws + WS_CPART;
    const unsigned short* __restrict__ wmT = (const unsigned short*)(ws + WS_WMT);

    const int t    = threadIdx.x;
    const int lane = t & 63;
    const int wave = t >> 6;

    const int row16 = lane & 15;
    const int kb    = lane >> 4;

    // ---- B fragments: 8 x 16B from global WmT (L2-hot), once ----
    bf16x8 bfr[2][4];                               // [kstep][ntile]
    #pragma unroll
    for (int ks = 0; ks < 2; ++ks)
        #pragma unroll
        for (int nn = 0; nn < 4; ++nn)
            bfr[ks][nn] = *(const bf16x8*)
                &wmT[(nn * 16 + row16) * DF + ks * 32 + kb * 8];

    // ---- per-wave query ----
    const int gw = blockIdx.x * 4 + wave;           // s*NQ + n
    const int s  = gw >> 14;
    const int n  = gw & (NQ - 1);
    const unsigned short* __restrict__ fTm =
        (const unsigned short*)(ws + WS_FT) + (size_t)s * MAPSZ_US;
    const int b = b_ids[n];
    const int Y = cy[n];
    const int X = cx[n];
    const int base = ((b * HF + (Y - 2)) * WF + (X - 2)) * DF;  // ushort idx

    // window rows this lane reads: w0 (tile0), w1 (tile1, clamped)
    const int w0  = row16;
    const int w1  = (row16 < 9) ? (16 + row16) : 24;
    const int wy0 = (w0 * 13) >> 6;                 // w/5 for w<25
    const int wy1 = (w1 * 13) >> 6;
    const unsigned short* __restrict__ fq0 =
        fTm + base + (wy0 * WF + (w0 - wy0 * 5)) * DF + kb * 8;
    const unsigned short* __restrict__ fq1 =
        fTm + base + (wy1 * WF + (w1 - wy1 * 5)) * DF + kb * 8;

    // ---- A fragments: 4 x 16B direct global loads ----
    const bf16x8 a00 = *(const bf16x8*)(fq0);       // m=0, ks=0
    const bf16x8 a01 = *(const bf16x8*)(fq0 + 32);  // m=0, ks=1
    const bf16x8 a10 = *(const bf16x8*)(fq1);       // m=1, ks=0
    const bf16x8 a11 = *(const bf16x8*)(fq1 + 32);  // m=1, ks=1

    f32x4 acc[2][4];
    #pragma unroll
    for (int m = 0; m < 2; ++m)
        #pragma unroll
        for (int nn = 0; nn < 4; ++nn)
            acc[m][nn] = (f32x4){0.f, 0.f, 0.f, 0.f};

    #pragma unroll
    for (int nn = 0; nn < 4; ++nn) {
        acc[0][nn] = __builtin_amdgcn_mfma_f32_16x16x32_bf16(a00, bfr[0][nn], acc[0][nn], 0, 0, 0);
        acc[1][nn] = __builtin_amdgcn_mfma_f32_16x16x32_bf16(a10, bfr[0][nn], acc[1][nn], 0, 0, 0);
        acc[0][nn] = __builtin_amdgcn_mfma_f32_16x16x32_bf16(a01, bfr[1][nn], acc[0][nn], 0, 0, 0);
        acc[1][nn] = __builtin_amdgcn_mfma_f32_16x16x32_bf16(a11, bfr[1][nn], acc[1][nn], 0, 0, 0);
    }

    // ---- epilogue: + cpart, nontemporal store (keep maps L3-resident) ----
    const float* __restrict__ cprow = cpart + (size_t)gw * DF;
    float* __restrict__ ob = out + (size_t)gw * (WW * DF);
    #pragma unroll
    for (int nn = 0; nn < 4; ++nn) {
        const float cp = cprow[nn * 16 + row16];
        #pragma unroll
        for (int m = 0; m < 2; ++m) {
            #pragma unroll
            for (int r = 0; r < 4; ++r) {
                const int w = m * 16 + kb * 4 + r;  // D row
                if (w < WW)
                    __builtin_nontemporal_store(
                        acc[m][nn][r] + cp, &ob[w * DF + nn * 16 + row16]);
            }
        }
    }
}

// ---------------- K2 (fallback): fp32 gather from channels-first ----------
__global__ __launch_bounds__(256) void k2_main(
    const float* __restrict__ f0, const float* __restrict__ f1,
    const float* __restrict__ Wm,
    const int* __restrict__ b_ids, const int* __restrict__ cy,
    const int* __restrict__ cx,
    const float* __restrict__ ws, float* __restrict__ out)
{
    const float* __restrict__ cpart = ws + WS_CPART;

    const int t    = threadIdx.x;
    const int lane = t & 63;
    const int wave = t >> 6;

    __shared__ float wm_sh[DF * DF];
    __shared__ float f_sh[4 * WW * FPAD];

    {
        const float4* src = (const float4*)Wm;
        float4* dst = (float4*)wm_sh;
        #pragma unroll
        for (int q = 0; q < 4; ++q)
            dst[t + q * 256] = src[t + q * 256];
    }

    const int gw = blockIdx.x * 4 + wave;
    const int s  = gw >> 14;
    const int n  = gw & (NQ - 1);
    const float* __restrict__ ff = s ? f1 : f0;
    const int b = b_ids[n];
    const int Y = cy[n];
    const int X = cx[n];

    float* fw = f_sh + wave * WW * FPAD;
    const float* fwin = ff + (size_t)b * BS_STRIDE_F + (size_t)(Y - 2) * WF + (X - 2);
    #pragma unroll
    for (int r = 0; r < 25; ++r) {
        const int e = lane + r * 64;
        const int i = e / 25;
        const int w = e - i * 25;
        const int wy = w / 5;
        const int wx = w - wy * 5;
        fw[w * FPAD + i] = fwin[(size_t)i * CH_STRIDE + wy * WF + wx];
    }
    __syncthreads();

    const int j0 = (lane & 15) * 4;
    const int w0 = lane >> 4;

    const float4 cp = *(const float4*)&cpart[(size_t)gw * DF + j0];
    float4 acc[7];
    #pragma unroll
    for (int u = 0; u < 7; ++u) acc[u] = cp;

    #pragma unroll 4
    for (int i = 0; i < DF; i += 4) {
        const float4 m0 = *(const float4*)&wm_sh[(i + 0) * DF + j0];
        const float4 m1 = *(const float4*)&wm_sh[(i + 1) * DF + j0];
        const float4 m2 = *(const float4*)&wm_sh[(i + 2) * DF + j0];
        const float4 m3 = *(const float4*)&wm_sh[(i + 3) * DF + j0];
        #pragma unroll
        for (int u = 0; u < 7; ++u) {
            const int w = w0 + 4 * u;
            if (w < WW) {
                const float4 fv = *(const float4*)&fw[w * FPAD + i];
                acc[u].x += fv.x * m0.x + fv.y * m1.x + fv.z * m2.x + fv.w * m3.x;
                acc[u].y += fv.x * m0.y + fv.y * m1.y + fv.z * m2.y + fv.w * m3.y;
                acc[u].z += fv.x * m0.z + fv.y * m1.z + fv.z * m2.z + fv.w * m3.z;
                acc[u].w += fv.x * m0.w + fv.y * m1.w + fv.z * m2.w + fv.w * m3.w;
            }
        }
    }

    float* ob = out + (size_t)gw * (WW * DF);
    #pragma unroll
    for (int u = 0; u < 7; ++u) {
        const int w = w0 + 4 * u;
        if (w < WW)
            *(float4*)&ob[w * DF + j0] = acc[u];
    }
}

extern "C" void kernel_launch(void* const* d_in, const int* in_sizes, int n_in,
                              void* d_out, int out_size, void* d_ws, size_t ws_size,
                              hipStream_t stream) {
    const float* f0 = (const float*)d_in[0];
    const float* f1 = (const float*)d_in[1];
    const float* c0 = (const float*)d_in[2];
    const float* c1 = (const float*)d_in[3];
    const float* Wd = (const float*)d_in[4];
    const float* bd = (const float*)d_in[5];
    const float* Wm = (const float*)d_in[6];
    const float* bm = (const float*)d_in[7];
    const int* b_ids = (const int*)d_in[8];
    const int* cyv   = (const int*)d_in[9];
    const int* cxv   = (const int*)d_in[10];
    const int* civ   = (const int*)d_in[11];
    float* out = (float*)d_out;
    float* ws  = (float*)d_ws;

    const bool big_ws = (ws_size >= WS_NEEDED_BYTES);

    if (big_ws) {
        kt_transpose<<<dim3(CH_STRIDE / 64, 4, 2), dim3(256), 0, stream>>>(f0, f1, ws);
    }
    k0_fuse_weights<<<dim3(DC + 2), dim3(64), 0, stream>>>(Wd, bd, Wm, bm, ws);
    k1_cpart<<<dim3(2 * NQ / K1_ROWS), dim3(256), 0, stream>>>(c0, c1, b_ids, civ, ws);
    if (big_ws) {
        k2_mfma<<<dim3(2 * NQ / 4), dim3(256), 0, stream>>>(
            b_ids, cyv, cxv, ws, out);
    } else {
        k2_main<<<dim3(2 * NQ / 4), dim3(256), 0, stream>>>(
            f0, f1, Wm, b_ids, cyv, cxv, ws, out);
    }
}

// Round 6
// 429.852 us; speedup vs baseline: 1.9174x; 1.0193x over previous
//
#include <hip/hip_runtime.h>

#define WIN 5
#define WW 25
#define DF 64
#define DC 256
#define HF 240
#define WF 320
#define LC 4800
#define NQ 16384
#define CH_STRIDE ((size_t)HF * WF)          // 76800
#define BS_STRIDE_F ((size_t)DF * CH_STRIDE)
#define FPAD 68          // LDS row stride (floats) for staging tiles

// d_ws float-index layout
#define WS_WFUSED 0                          // 256*64 floats
#define WS_BFUSED (DC * DF)                  // 64 floats (+pad)
#define WS_CPART  (DC * DF + 256)            // 32768*64 floats
#define WS_WMT    (WS_CPART + 2 * NQ * DF)   // 64x64 bf16 WmT (2048 floats)
#define WS_FT     (WS_WMT + 2048)            // bf16 channels-last maps
#define MAPSZ_US  ((size_t)4 * CH_STRIDE * DF)       // 19,660,800 ushorts/map
#define WS_NEEDED_BYTES ((size_t)WS_FT * 4 + 2 * MAPSZ_US * 2)   // ~87 MB

typedef __attribute__((ext_vector_type(8))) short bf16x8;   // 8 bf16 (4 VGPR)
typedef __attribute__((ext_vector_type(4))) float f32x4;

__device__ __forceinline__ unsigned short f2bf(float x) {   // RNE f32->bf16
    unsigned int u = __float_as_uint(x);
    u += 0x7FFFu + ((u >> 16) & 1u);
    return (unsigned short)(u >> 16);
}

// ---------------- K0: Wfused = Wd @ Wm_bot, bfused, WmT(bf16) -------------
__global__ __launch_bounds__(64) void k0_fuse_weights(
    const float* __restrict__ Wd, const float* __restrict__ bd,
    const float* __restrict__ Wm, const float* __restrict__ bm,
    float* __restrict__ ws)
{
    const int r = blockIdx.x;      // 0..255 Wfused row; 256 bfused; 257 WmT
    const int j = threadIdx.x;     // 0..63
    if (r < DC) {
        float acc = 0.f;
        #pragma unroll 8
        for (int i = 0; i < DF; ++i)
            acc += Wd[r * DF + i] * Wm[(DF + i) * DF + j];
        ws[WS_WFUSED + r * DF + j] = acc;
    } else if (r == DC) {
        float acc = bm[j];
        #pragma unroll 8
        for (int i = 0; i < DF; ++i)
            acc += bd[i] * Wm[(DF + i) * DF + j];
        ws[WS_BFUSED + j] = acc;
    } else {
        // WmT[j][i] = bf16(Wm_top[i][j])  (8 KB, once)
        unsigned short* __restrict__ wmT = (unsigned short*)(ws + WS_WMT);
        #pragma unroll 8
        for (int i = 0; i < DF; ++i)
            wmT[j * DF + i] = f2bf(Wm[i * DF + j]);
    }
}

// ---------------- K1: cpart[row][j] = bfused[j] + c[row] . Wfused[:,j] -----
// software-pipelined: row ri+1's c-load issues before row ri's compute.
#define K1_ROWS 16
__global__ __launch_bounds__(256) void k1_cpart(
    const float* __restrict__ c0, const float* __restrict__ c1,
    const int* __restrict__ b_ids, const int* __restrict__ ci,
    float* __restrict__ ws)
{
    const float* __restrict__ wfused = ws + WS_WFUSED;
    const float* __restrict__ bfused = ws + WS_BFUSED;
    float* __restrict__ cpart = ws + WS_CPART;

    const int t  = threadIdx.x;
    const int j  = t & 63;
    const int kc = t >> 6;

    float wf[64];
    #pragma unroll
    for (int k = 0; k < 64; ++k)
        wf[k] = wfused[(kc * 64 + k) * DF + j];

    __shared__ float c_sh[DC];
    __shared__ float red[256];

    // prologue: load row 0
    auto load_c = [&](int row) -> float {
        const int s = row >> 14;
        const int n = row & (NQ - 1);
        const float* __restrict__ fc = s ? c1 : c0;
        return fc[((size_t)b_ids[n] * LC + ci[n]) * DC + t];
    };
    float c_cur = load_c(blockIdx.x * K1_ROWS);

    for (int ri = 0; ri < K1_ROWS; ++ri) {
        const int row = blockIdx.x * K1_ROWS + ri;
        c_sh[t] = c_cur;
        __syncthreads();

        // issue next row's load early (hidden under compute)
        if (ri + 1 < K1_ROWS) c_cur = load_c(row + 1);

        float acc = 0.f;
        #pragma unroll
        for (int k4 = 0; k4 < 16; ++k4) {
            float4 cv = *(const float4*)&c_sh[kc * 64 + k4 * 4];
            acc += cv.x * wf[k4 * 4 + 0] + cv.y * wf[k4 * 4 + 1] +
                   cv.z * wf[k4 * 4 + 2] + cv.w * wf[k4 * 4 + 3];
        }
        red[t] = acc;
        __syncthreads();

        if (t < 64) {
            cpart[(size_t)row * DF + t] =
                red[t] + red[t + 64] + red[t + 128] + red[t + 192] + bfused[t];
        }
        // next-iter c_sh write is safe: all c_sh reads ended before red-barrier
    }
}

// ---------------- KT: channels-first fp32 -> channels-last bf16 -----------
__global__ __launch_bounds__(256) void kt_transpose(
    const float* __restrict__ f0, const float* __restrict__ f1,
    float* __restrict__ ws)
{
    const int t = threadIdx.x;
    const float* __restrict__ src = blockIdx.z ? f1 : f0;
    unsigned short* __restrict__ fT =
        (unsigned short*)(ws + WS_FT) + (size_t)blockIdx.z * MAPSZ_US;
    const int b  = blockIdx.y;
    const int p0 = blockIdx.x * 64;

    __shared__ float tile[64][65];

    const float* __restrict__ sb = src + (size_t)b * BS_STRIDE_F;
    const int g  = t >> 4;           // 0..15
    const int x4 = t & 15;
    #pragma unroll
    for (int q = 0; q < 4; ++q) {
        const int c = g + q * 16;
        const f32x4 v = __builtin_nontemporal_load(
            (const f32x4*)&sb[(size_t)c * CH_STRIDE + p0 + x4 * 4]);
        tile[c][x4 * 4 + 0] = v[0]; tile[c][x4 * 4 + 1] = v[1];
        tile[c][x4 * 4 + 2] = v[2]; tile[c][x4 * 4 + 3] = v[3];
    }
    __syncthreads();
    unsigned short* __restrict__ ob = fT + ((size_t)b * CH_STRIDE + p0) * DF;
    #pragma unroll
    for (int q = 0; q < 4; ++q) {
        const int p  = g + q * 16;
        const int cc = x4 * 4;
        ushort4 h;
        h.x = f2bf(tile[cc + 0][p]); h.y = f2bf(tile[cc + 1][p]);
        h.z = f2bf(tile[cc + 2][p]); h.w = f2bf(tile[cc + 3][p]);
        *(ushort4*)&ob[(size_t)p * DF + cc] = h;      // cacheable: k2 reads it
    }
}

// ---------------- K2M: MFMA, direct-register fragments, LDS-coalesced out -
// out[w][j] = cpart[gw][j] + sum_i f[w][i]*Wm_top[i][j]
// A-frags straight from channels-last bf16 map (16B/lane, no gather LDS).
// B-frags query-invariant per lane -> registers (L1-hot WmT).
// Epilogue: acc -> wave-private LDS (no barrier) -> 7x coalesced float4 NT
// stores (full 128B lines: full HBM write efficiency + no L3 pollution).
__global__ __launch_bounds__(256) void k2_mfma(
    const int* __restrict__ b_ids, const int* __restrict__ cy,
    const int* __restrict__ cx,
    const float* __restrict__ ws, float* __restrict__ out)
{
    const float* __restrict__ cpart = ws + WS_CPART;
    const unsigned short* __restrict__ wmT = (const unsigned short*)(ws + WS_WMT);

    const int t    = threadIdx.x;
    const int lane = t & 63;
    const int wave = t >> 6;

    const int row16 = lane & 15;
    const int kb    = lane >> 4;

    __shared__ float o_sh[4 * WW * FPAD];           // 27.2 KB epilogue staging

    // ---- per-wave query ----
    const int gw = blockIdx.x * 4 + wave;           // s*NQ + n
    const int s  = gw >> 14;
    const int n  = gw & (NQ - 1);
    const unsigned short* __restrict__ fTm =
        (const unsigned short*)(ws + WS_FT) + (size_t)s * MAPSZ_US;
    const int b = b_ids[n];
    const int Y = cy[n];
    const int X = cx[n];
    const int base = ((b * HF + (Y - 2)) * WF + (X - 2)) * DF;  // ushort idx

    // window rows this lane reads: w0 (tile0), w1 (tile1, clamped)
    const int w0  = row16;
    const int w1  = (row16 < 9) ? (16 + row16) : 24;
    const int wy0 = (w0 * 13) >> 6;                 // w/5 for w<25
    const int wy1 = (w1 * 13) >> 6;
    const unsigned short* __restrict__ fq0 =
        fTm + base + (wy0 * WF + (w0 - wy0 * 5)) * DF + kb * 8;
    const unsigned short* __restrict__ fq1 =
        fTm + base + (wy1 * WF + (w1 - wy1 * 5)) * DF + kb * 8;

    // ---- A fragments first (L3-latency path) ----
    const bf16x8 a00 = *(const bf16x8*)(fq0);       // m=0, ks=0
    const bf16x8 a01 = *(const bf16x8*)(fq0 + 32);  // m=0, ks=1
    const bf16x8 a10 = *(const bf16x8*)(fq1);       // m=1, ks=0
    const bf16x8 a11 = *(const bf16x8*)(fq1 + 32);  // m=1, ks=1

    // ---- B fragments (L1-hot 8KB WmT) ----
    bf16x8 bfr[2][4];                               // [kstep][ntile]
    #pragma unroll
    for (int ks = 0; ks < 2; ++ks)
        #pragma unroll
        for (int nn = 0; nn < 4; ++nn)
            bfr[ks][nn] = *(const bf16x8*)
                &wmT[(nn * 16 + row16) * DF + ks * 32 + kb * 8];

    f32x4 acc[2][4];
    #pragma unroll
    for (int m = 0; m < 2; ++m)
        #pragma unroll
        for (int nn = 0; nn < 4; ++nn)
            acc[m][nn] = (f32x4){0.f, 0.f, 0.f, 0.f};

    #pragma unroll
    for (int nn = 0; nn < 4; ++nn) {
        acc[0][nn] = __builtin_amdgcn_mfma_f32_16x16x32_bf16(a00, bfr[0][nn], acc[0][nn], 0, 0, 0);
        acc[1][nn] = __builtin_amdgcn_mfma_f32_16x16x32_bf16(a10, bfr[0][nn], acc[1][nn], 0, 0, 0);
        acc[0][nn] = __builtin_amdgcn_mfma_f32_16x16x32_bf16(a01, bfr[1][nn], acc[0][nn], 0, 0, 0);
        acc[1][nn] = __builtin_amdgcn_mfma_f32_16x16x32_bf16(a11, bfr[1][nn], acc[1][nn], 0, 0, 0);
    }

    // ---- epilogue: +cpart -> wave-private LDS (no barrier needed) ----
    const float* __restrict__ cprow = cpart + (size_t)gw * DF;
    float* osh = o_sh + wave * WW * FPAD;
    #pragma unroll
    for (int nn = 0; nn < 4; ++nn) {
        const float cp = cprow[nn * 16 + row16];
        #pragma unroll
        for (int m = 0; m < 2; ++m) {
            #pragma unroll
            for (int r = 0; r < 4; ++r) {
                const int w = m * 16 + kb * 4 + r;  // D row
                if (w < WW)
                    osh[w * FPAD + nn * 16 + row16] = acc[m][nn][r] + cp;
            }
        }
    }

    // ---- coalesced NT float4 stores: 7 x 1KB full-line wave-stores ----
    const int j4 = (lane & 15) * 4;
    const int wg = lane >> 4;
    float* __restrict__ ob = out + (size_t)gw * (WW * DF);
    #pragma unroll
    for (int u = 0; u < 7; ++u) {
        const int w = wg + 4 * u;
        if (w < WW) {
            const f32x4 v = *(const f32x4*)&osh[w * FPAD + j4];
            __builtin_nontemporal_store(v, (f32x4*)&ob[w * DF + j4]);
        }
    }
}

// ---------------- K2 (fallback): fp32 gather from channels-first ----------
__global__ __launch_bounds__(256) void k2_main(
    const float* __restrict__ f0, const float* __restrict__ f1,
    const float* __restrict__ Wm,
    const int* __restrict__ b_ids, const int* __restrict__ cy,
    const int* __restrict__ cx,
    const float* __restrict__ ws, float* __restrict__ out)
{
    const float* __restrict__ cpart = ws + WS_CPART;

    const int t    = threadIdx.x;
    const int lane = t & 63;
    const int wave = t >> 6;

    __shared__ float wm_sh[DF * DF];
    __shared__ float f_sh[4 * WW * FPAD];

    {
        const float4* src = (const float4*)Wm;
        float4* dst = (float4*)wm_sh;
        #pragma unroll
        for (int q = 0; q < 4; ++q)
            dst[t + q * 256] = src[t + q * 256];
    }

    const int gw = blockIdx.x * 4 + wave;
    const int s  = gw >> 14;
    const int n  = gw & (NQ - 1);
    const float* __restrict__ ff = s ? f1 : f0;
    const int b = b_ids[n];
    const int Y = cy[n];
    const int X = cx[n];

    float* fw = f_sh + wave * WW * FPAD;
    const float* fwin = ff + (size_t)b * BS_STRIDE_F + (size_t)(Y - 2) * WF + (X - 2);
    #pragma unroll
    for (int r = 0; r < 25; ++r) {
        const int e = lane + r * 64;
        const int i = e / 25;
        const int w = e - i * 25;
        const int wy = w / 5;
        const int wx = w - wy * 5;
        fw[w * FPAD + i] = fwin[(size_t)i * CH_STRIDE + wy * WF + wx];
    }
    __syncthreads();

    const int j0 = (lane & 15) * 4;
    const int w0 = lane >> 4;

    const float4 cp = *(const float4*)&cpart[(size_t)gw * DF + j0];
    float4 acc[7];
    #pragma unroll
    for (int u = 0; u < 7; ++u) acc[u] = cp;

    #pragma unroll 4
    for (int i = 0; i < DF; i += 4) {
        const float4 m0 = *(const float4*)&wm_sh[(i + 0) * DF + j0];
        const float4 m1 = *(const float4*)&wm_sh[(i + 1) * DF + j0];
        const float4 m2 = *(const float4*)&wm_sh[(i + 2) * DF + j0];
        const float4 m3 = *(const float4*)&wm_sh[(i + 3) * DF + j0];
        #pragma unroll
        for (int u = 0; u < 7; ++u) {
            const int w = w0 + 4 * u;
            if (w < WW) {
                const float4 fv = *(const float4*)&fw[w * FPAD + i];
                acc[u].x += fv.x * m0.x + fv.y * m1.x + fv.z * m2.x + fv.w * m3.x;
                acc[u].y += fv.x * m0.y + fv.y * m1.y + fv.z * m2.y + fv.w * m3.y;
                acc[u].z += fv.x * m0.z + fv.y * m1.z + fv.z * m2.z + fv.w * m3.z;
                acc[u].w += fv.x * m0.w + fv.y * m1.w + fv.z * m2.w + fv.w * m3.w;
            }
        }
    }

    float* ob = out + (size_t)gw * (WW * DF);
    #pragma unroll
    for (int u = 0; u < 7; ++u) {
        const int w = w0 + 4 * u;
        if (w < WW)
            *(float4*)&ob[w * DF + j0] = acc[u];
    }
}

extern "C" void kernel_launch(void* const* d_in, const int* in_sizes, int n_in,
                              void* d_out, int out_size, void* d_ws, size_t ws_size,
                              hipStream_t stream) {
    const float* f0 = (const float*)d_in[0];
    const float* f1 = (const float*)d_in[1];
    const float* c0 = (const float*)d_in[2];
    const float* c1 = (const float*)d_in[3];
    const float* Wd = (const float*)d_in[4];
    const float* bd = (const float*)d_in[5];
    const float* Wm = (const float*)d_in[6];
    const float* bm = (const float*)d_in[7];
    const int* b_ids = (const int*)d_in[8];
    const int* cyv   = (const int*)d_in[9];
    const int* cxv   = (const int*)d_in[10];
    const int* civ   = (const int*)d_in[11];
    float* out = (float*)d_out;
    float* ws  = (float*)d_ws;

    const bool big_ws = (ws_size >= WS_NEEDED_BYTES);

    if (big_ws) {
        kt_transpose<<<dim3(CH_STRIDE / 64, 4, 2), dim3(256), 0, stream>>>(f0, f1, ws);
    }
    k0_fuse_weights<<<dim3(DC + 2), dim3(64), 0, stream>>>(Wd, bd, Wm, bm, ws);
    k1_cpart<<<dim3(2 * NQ / K1_ROWS), dim3(256), 0, stream>>>(c0, c1, b_ids, civ, ws);
    if (big_ws) {
        k2_mfma<<<dim3(2 * NQ / 4), dim3(256), 0, stream>>>(
            b_ids, cyv, cxv, ws, out);
    } else {
        k2_main<<<dim3(2 * NQ / 4), dim3(256), 0, stream>>>(
            f0, f1, Wm, b_ids, cyv, cxv, ws, out);
    }
}